// Round 16
// baseline (186.169 us; speedup 1.0000x reference)
//
#include <hip/hip_runtime.h>
#include <hip/hip_bf16.h>

using short8 = __attribute__((ext_vector_type(8))) short;
using half8  = __attribute__((ext_vector_type(8))) _Float16;
using f32x4  = __attribute__((ext_vector_type(4))) float;

constexpr int Bdim = 16;
constexpr int Tdim = 1024;
constexpr int Sdim = 1024;
constexpr int Ddim = 1024;

__device__ __forceinline__ unsigned short f2hu(float x) {
  _Float16 h = (_Float16)x;
  return __builtin_bit_cast(unsigned short, h);
}
__device__ __forceinline__ float hu2f(unsigned short u) {
  return (float)__builtin_bit_cast(_Float16, u);
}

// ---------- fp32 -> fp16 single ----------
__global__ void __launch_bounds__(256)
conv_kernel(const float* __restrict__ src, unsigned short* __restrict__ dst, int n4) {
  int i = blockIdx.x * blockDim.x + threadIdx.x;
  int stride = gridDim.x * blockDim.x;
  for (; i < n4; i += stride) {
    float4 v = reinterpret_cast<const float4*>(src)[i];
    ushort4 h;
    h.x = f2hu(v.x); h.y = f2hu(v.y); h.z = f2hu(v.z); h.w = f2hu(v.w);
    reinterpret_cast<ushort4*>(dst)[i] = h;
  }
}

// ---------- ctx [B,S,D] fp32 -> ctx16 [B,S,D] fp16 AND ctxT [B,D,S] fp16 ----------
__global__ void __launch_bounds__(256)
ctxprep_kernel(const float* __restrict__ ctx, unsigned short* __restrict__ ctx16,
               unsigned short* __restrict__ ctxT) {
  __shared__ float tile[64][65];
  int b = blockIdx.z;
  int d0 = blockIdx.x * 64, s0 = blockIdx.y * 64;
  const float* src = ctx + (size_t)b * Sdim * Ddim;
  unsigned short* dstS = ctx16 + (size_t)b * Sdim * Ddim;
  unsigned short* dstT = ctxT + (size_t)b * Ddim * Sdim;
  int tx = threadIdx.x & 15, ty = threadIdx.x >> 4;
  #pragma unroll
  for (int r = 0; r < 4; ++r) {
    int s = ty + r * 16;
    float4 v = reinterpret_cast<const float4*>(src + (size_t)(s0 + s) * Ddim + d0)[tx];
    ushort4 hs;
    hs.x = f2hu(v.x); hs.y = f2hu(v.y); hs.z = f2hu(v.z); hs.w = f2hu(v.w);
    reinterpret_cast<ushort4*>(dstS + (size_t)(s0 + s) * Ddim + d0)[tx] = hs;
    tile[s][tx * 4 + 0] = v.x; tile[s][tx * 4 + 1] = v.y;
    tile[s][tx * 4 + 2] = v.z; tile[s][tx * 4 + 3] = v.w;
  }
  __syncthreads();
  #pragma unroll
  for (int r = 0; r < 4; ++r) {
    int d = ty + r * 16;
    ushort4 o;
    o.x = f2hu(tile[tx * 4 + 0][d]);
    o.y = f2hu(tile[tx * 4 + 1][d]);
    o.z = f2hu(tile[tx * 4 + 2][d]);
    o.w = f2hu(tile[tx * 4 + 3][d]);
    reinterpret_cast<ushort4*>(dstT + (size_t)(d0 + d) * Sdim + s0)[tx] = o;
  }
}

#define MFMAH(d, x, y)                                                          \
  d = __builtin_amdgcn_mfma_f32_16x16x32_f16(__builtin_bit_cast(half8, (x)),    \
                                             __builtin_bit_cast(half8, (y)), (d), 0, 0, 0)

#define GLOADLDS(g, l)                                                          \
  __builtin_amdgcn_global_load_lds((const __attribute__((address_space(1))) void*)(g), \
                                   (__attribute__((address_space(3))) void*)(l), 16, 0, 0)

// ---------- PLAIN fp16 GEMM: 128x128 tile, BK=64, dbuf 64 KiB, 2 blocks/CU ----------
// r16: FIX of r14/r15 NaN — gemmQ's LDS-DMA dest was not lane-linear (m104:
// global_load_lds = wave-uniform base + lane*16B). Staging is now per-wave
// 1KB-chunk: dest = chunk_base + lane*16B; source row = chunk*8 + (lane>>3),
// source granule (lane&7)^(lane>>3) keeps phys[p]=glob[p^(row&7)] so the
// read-side swizzle is unchanged. Clean exit (no tail re-stage).
// MODE 1: out f32 at (rr*16+bb)*1024+cc ; MODE 2: out fp16 at rr*1024+cc
template <int MODE>
__global__ void __launch_bounds__(512, 4)
gemmQ(const unsigned short* __restrict__ Ag, const unsigned short* __restrict__ Bg,
      size_t aBatch, size_t bBatch, int mnShift,
      unsigned short* __restrict__ outH, float* __restrict__ outF) {
  constexpr int NT = 16;                               // BK = 64
  __shared__ __align__(16) unsigned short lds[2 * 16384];  // [buf][A 16KB | B 16KB]

  // XCD-chunked bijective swizzle over 1024 blocks (= 8 * 128)
  const int hw = blockIdx.x;
  const int L  = (hw & 7) * 128 + (hw >> 3);
  const int bb = L >> mnShift;
  const int r  = L & ((1 << mnShift) - 1);
  const int m0 = (r >> 3) * 128;
  const int n0 = (r & 7) * 128;

  const int tid  = threadIdx.x;
  const int lane = tid & 63;
  const int w    = tid >> 6;          // 8 waves: 2(M) x 4(N)
  const int wr   = (w >> 2) * 64;
  const int wc   = (w & 3) * 32;
  const int l15  = lane & 15;
  const int g0   = lane >> 4;
  const int r7   = l15 & 7;

  // per-wave chunk staging (lane-linear DMA dest):
  // chunk = 8 rows x 128B = 1KB; wave w owns chunks {2w, 2w+1} of A and of B.
  const int crow = lane >> 3;          // row within chunk (0..7)
  const int cg   = (lane & 7) ^ crow;  // pre-swizzled source granule
  const int ca   = w * 2;              // first chunk index
  const unsigned short* pA0 = Ag + (size_t)bb * aBatch + (size_t)(m0 + ca * 8 + crow) * 1024 + cg * 8;
  const unsigned short* pA1 = pA0 + 8 * 1024;   // chunk ca+1 = +8 rows
  const unsigned short* pB0 = Bg + (size_t)bb * bBatch + (size_t)(n0 + ca * 8 + crow) * 1024 + cg * 8;
  const unsigned short* pB1 = pB0 + 8 * 1024;
  const int d0 = ca * 512 + lane * 8;  // ushort offset: chunk_base + lane*16B
  const int d1 = d0 + 512;

  auto stage = [&](int buf, int kt) {   // 4 loads/thread, each a contiguous 1KB/wave
    unsigned short* base = lds + buf * 16384;
    GLOADLDS(pA0 + kt * 64, base + d0);
    GLOADLDS(pA1 + kt * 64, base + d1);
    GLOADLDS(pB0 + kt * 64, base + 8192 + d0);
    GLOADLDS(pB1 + kt * 64, base + 8192 + d1);
  };

  f32x4 acc[4][2];
  const f32x4 vzero = {0.f, 0.f, 0.f, 0.f};
  #pragma unroll
  for (int f = 0; f < 4; ++f) { acc[f][0] = vzero; acc[f][1] = vzero; }

  stage(0, 0);

  #pragma unroll 1
  for (int t = 0; t < NT; ++t) {
    if (t + 1 < NT) {
      stage((t + 1) & 1, t + 1);
      // drain tile t's 4 loads; leave t+1's 4 in flight
      asm volatile("s_waitcnt vmcnt(4)" ::: "memory");
    } else {
      // last round: drain everything -> 0 outstanding DMAs at exit
      asm volatile("s_waitcnt vmcnt(0)" ::: "memory");
    }
    __builtin_amdgcn_s_barrier();
    asm volatile("" ::: "memory");
    const unsigned short* tb = lds + (t & 1) * 16384;
    const unsigned short* tB = tb + 8192;

    short8 bf[2][2], af[4][2];
    #pragma unroll
    for (int j = 0; j < 2; ++j) {
      const int row = wc + j * 16 + l15;
      #pragma unroll
      for (int kk = 0; kk < 2; ++kk)
        bf[j][kk] = *reinterpret_cast<const short8*>(tB + row * 64 + ((kk * 4 + g0) ^ r7) * 8);
    }
    #pragma unroll
    for (int f = 0; f < 4; ++f) {
      const int row = wr + f * 16 + l15;
      #pragma unroll
      for (int kk = 0; kk < 2; ++kk)
        af[f][kk] = *reinterpret_cast<const short8*>(tb + row * 64 + ((kk * 4 + g0) ^ r7) * 8);
    }
    asm volatile("s_waitcnt lgkmcnt(0)" ::: "memory");
    __builtin_amdgcn_sched_barrier(0);
    __builtin_amdgcn_s_setprio(1);
    #pragma unroll
    for (int f = 0; f < 4; ++f)
      #pragma unroll
      for (int j = 0; j < 2; ++j)
        #pragma unroll
        for (int kk = 0; kk < 2; ++kk)
          MFMAH(acc[f][j], af[f][kk], bf[j][kk]);
    __builtin_amdgcn_s_setprio(0);
    __builtin_amdgcn_sched_barrier(0);
    __builtin_amdgcn_s_barrier();
  }

  // epilogue: C/D layout col=lane&15, row=(lane>>4)*4+q (m89/m91 verified)
  const int lr = (lane >> 4) * 4;
  const int lc = lane & 15;
  #pragma unroll
  for (int f = 0; f < 4; ++f)
    #pragma unroll
    for (int j = 0; j < 2; ++j)
      #pragma unroll
      for (int q = 0; q < 4; ++q) {
        int rr = m0 + wr + f * 16 + lr + q;
        int cc = n0 + wc + j * 16 + lc;
        float v = acc[f][j][q];
        if constexpr (MODE == 2) {
          outH[(size_t)rr * 1024 + cc] = f2hu(v);
        } else {
          outF[((size_t)rr * 16 + bb) * 1024 + cc] = v;
        }
      }
}

// ---------- FUSED K2+softmax: 64x1024 tile (full S row), BK=64, NT=16 ----------
// (unchanged from r11-r13 — verified passing)
__global__ void __launch_bounds__(512, 2)
gemmF(const unsigned short* __restrict__ Hh, const unsigned short* __restrict__ Cg,
      float* __restrict__ alignOut, unsigned short* __restrict__ pOut) {
  constexpr int NT = 16;
  __shared__ __align__(16) unsigned short lds[2 * 4096 + 65536];  // A dbuf + B

  const int hw = blockIdx.x;                 // 256 blocks
  const int L  = (hw & 7) * 32 + (hw >> 3);  // XCD-chunked
  const int bb = L >> 4;                     // 16 batches
  const int m0 = (L & 15) * 64;              // 16 M-blocks of 64 rows

  const int tid  = threadIdx.x;
  const int lane = tid & 63;
  const int w    = tid >> 6;          // 8 waves: 1(M) x 8(N)
  const int l15  = lane & 15;
  const int g0   = lane >> 4;

  const int srow = tid >> 3;          // 0..63
  const int sg   = tid & 7;
  const int rs   = srow & 7;
  const unsigned short* spA = Hh + (size_t)bb * (Tdim * Ddim) + (size_t)(m0 + srow) * 1024 + ((sg ^ rs) * 8);
  const unsigned short* spB = Cg + (size_t)bb * (Sdim * Ddim) + (size_t)srow * 1024 + ((sg ^ rs) * 8);

  unsigned short* const ldsB = lds + 8192;

  auto stageA = [&](int buf, int kt) {       // 1 instr/thread (8KB tile)
    GLOADLDS(spA + kt * 64, lds + buf * 4096 + tid * 8);
  };
  auto stageB = [&](int kt) {                // 16 instr/thread (128KB)
    #pragma unroll
    for (int i = 0; i < 16; ++i)
      GLOADLDS(spB + (size_t)i * (64 * 1024) + kt * 64, ldsB + i * 4096 + tid * 8);
  };

  f32x4 acc[4][8];
  const f32x4 vzero = {0.f, 0.f, 0.f, 0.f};
  #pragma unroll
  for (int f = 0; f < 4; ++f)
    #pragma unroll
    for (int j = 0; j < 8; ++j) acc[f][j] = vzero;

  stageA(0, 0);
  stageB(0);
  stageA(1, 1);
  asm volatile("s_waitcnt vmcnt(1)" ::: "memory");
  __builtin_amdgcn_s_barrier();

  #pragma unroll 1
  for (int t = 0; t < NT; ++t) {
    const unsigned short* tA = lds + (t & 1) * 4096;

    short8 bf[8][2];
    #pragma unroll
    for (int j = 0; j < 8; ++j) {
      const int row = w * 128 + j * 16 + l15;
      #pragma unroll
      for (int kk = 0; kk < 2; ++kk)
        bf[j][kk] = *reinterpret_cast<const short8*>(ldsB + row * 64 + ((kk * 4 + g0) ^ (row & 7)) * 8);
    }
    short8 af[4][2];
    #pragma unroll
    for (int f = 0; f < 4; ++f) {
      const int row = f * 16 + l15;
      #pragma unroll
      for (int kk = 0; kk < 2; ++kk)
        af[f][kk] = *reinterpret_cast<const short8*>(tA + row * 64 + ((kk * 4 + g0) ^ (row & 7)) * 8);
    }
    asm volatile("s_waitcnt lgkmcnt(0)" ::: "memory");
    __builtin_amdgcn_sched_barrier(0);
    __builtin_amdgcn_s_barrier();          // all LDS reads retired -> buffers free

    if (t + 1 < NT) stageB(t + 1);         // restage B under MFMA phase
    if (t + 2 < NT) stageA(t & 1, t + 2);

    __builtin_amdgcn_s_setprio(1);
    #pragma unroll
    for (int f = 0; f < 4; ++f)
      #pragma unroll
      for (int j = 0; j < 8; ++j)
        #pragma unroll
        for (int kk = 0; kk < 2; ++kk)
          MFMAH(acc[f][j], af[f][kk], bf[j][kk]);
    __builtin_amdgcn_s_setprio(0);

    if (t + 1 < NT) {
      if (t + 2 < NT) asm volatile("s_waitcnt vmcnt(1)" ::: "memory");
      else            asm volatile("s_waitcnt vmcnt(0)" ::: "memory");
    }
    __builtin_amdgcn_s_barrier();
  }

  // ---- fused row softmax over full S=1024 ----
  float* red = (float*)lds;                 // reuse A region: [64][8] f32
  const int lr = (lane >> 4) * 4;

  float rmax[4][4];
  #pragma unroll
  for (int f = 0; f < 4; ++f)
    #pragma unroll
    for (int q = 0; q < 4; ++q) {
      float m = acc[f][0][q];
      #pragma unroll
      for (int j = 1; j < 8; ++j) m = fmaxf(m, acc[f][j][q]);
      #pragma unroll
      for (int o = 1; o < 16; o <<= 1) m = fmaxf(m, __shfl_xor(m, o));
      rmax[f][q] = m;
    }
  if (l15 == 0) {
    #pragma unroll
    for (int f = 0; f < 4; ++f)
      #pragma unroll
      for (int q = 0; q < 4; ++q) red[(f * 16 + lr + q) * 8 + w] = rmax[f][q];
  }
  __syncthreads();
  #pragma unroll
  for (int f = 0; f < 4; ++f)
    #pragma unroll
    for (int q = 0; q < 4; ++q) {
      const float* rr = red + (f * 16 + lr + q) * 8;
      float m = rr[0];
      #pragma unroll
      for (int k = 1; k < 8; ++k) m = fmaxf(m, rr[k]);
      rmax[f][q] = m;
    }
  __syncthreads();

  float rsum[4][4];
  #pragma unroll
  for (int f = 0; f < 4; ++f)
    #pragma unroll
    for (int q = 0; q < 4; ++q) {
      float s = 0.f;
      #pragma unroll
      for (int j = 0; j < 8; ++j) {
        float e = __expf(acc[f][j][q] - rmax[f][q]);
        acc[f][j][q] = e;
        s += e;
      }
      #pragma unroll
      for (int o = 1; o < 16; o <<= 1) s += __shfl_xor(s, o);
      rsum[f][q] = s;
    }
  if (l15 == 0) {
    #pragma unroll
    for (int f = 0; f < 4; ++f)
      #pragma unroll
      for (int q = 0; q < 4; ++q) red[(f * 16 + lr + q) * 8 + w] = rsum[f][q];
  }
  __syncthreads();
  #pragma unroll
  for (int f = 0; f < 4; ++f)
    #pragma unroll
    for (int q = 0; q < 4; ++q) {
      const float* rr = red + (f * 16 + lr + q) * 8;
      float s = ((rr[0] + rr[1]) + (rr[2] + rr[3])) + ((rr[4] + rr[5]) + (rr[6] + rr[7]));
      rsum[f][q] = 1.0f / s;
    }

  #pragma unroll
  for (int f = 0; f < 4; ++f)
    #pragma unroll
    for (int q = 0; q < 4; ++q) {
      const int row = m0 + f * 16 + lr + q;
      float inv = rsum[f][q];
      #pragma unroll
      for (int j = 0; j < 8; ++j) {
        const int cc = w * 128 + j * 16 + l15;
        float v = acc[f][j][q] * inv;
        alignOut[((size_t)row * 16 + bb) * 1024 + cc] = v;
        pOut[((size_t)bb * 1024 + row) * 1024 + cc] = f2hu(v);
      }
    }
}

extern "C" void kernel_launch(void* const* d_in, const int* in_sizes, int n_in,
                              void* d_out, int out_size, void* d_ws, size_t ws_size,
                              hipStream_t stream) {
  const float* input = (const float*)d_in[0];  // [B,T,D]
  const float* ctx   = (const float*)d_in[1];  // [B,S,D]
  const float* Wt    = (const float*)d_in[2];  // [D,D]
  float* attn_out  = (float*)d_out;                               // [T,B,D]
  float* align_out = attn_out + (size_t)Tdim * Bdim * Ddim;       // [T,B,S]

  const size_t NE = (size_t)Bdim * Tdim * Ddim;  // 16M elems
  unsigned short* x16  = (unsigned short*)d_ws;  // 32MB, reused as ctx16 after K1
  unsigned short* Wh   = x16 + NE;               // 2MB
  unsigned short* hh   = Wh + (size_t)Ddim * Ddim;  // 32MB, overwritten by p in gemmF
  unsigned short* ctxT = hh + NE;                // 32MB
  unsigned short* ctx16 = x16;
  unsigned short* p     = hh;

  conv_kernel<<<2048, 256, 0, stream>>>(input, x16, (int)(NE / 4));
  conv_kernel<<<512, 256, 0, stream>>>(Wt, Wh, (int)((size_t)Ddim * Ddim / 4));
  // K1: h = x @ W^T, plain fp16 -> hh (M=16384: 128 M-tiles x 8 N-tiles)
  gemmQ<2><<<1024, 512, 0, stream>>>(x16, Wh, 0, 0, 10, hh, nullptr);
  // ctx16 [B,S,D] + ctxT [B,D,S] fp16 (ctx16 into dead x region)
  ctxprep_kernel<<<dim3(16, 16, Bdim), 256, 0, stream>>>(ctx, ctx16, ctxT);
  // K2 fused: align = softmax(h @ ctx^T) -> align_out f32 [T,B,S], p fp16
  gemmF<<<256, 512, 0, stream>>>(hh, ctx16, align_out, p);
  // K4: attn = p @ ctx, plain fp16 -> f32 [T,B,D] (16 batches x 8x8 tiles)
  gemmQ<1><<<1024, 512, 0, stream>>>(p, ctxT, (size_t)Tdim * Sdim,
                                     (size_t)Ddim * Sdim, 6, nullptr, attn_out);
}

// Round 17
// 183.141 us; speedup vs baseline: 1.0165x; 1.0165x over previous
//
#include <hip/hip_runtime.h>
#include <hip/hip_bf16.h>

using short8 = __attribute__((ext_vector_type(8))) short;
using half8  = __attribute__((ext_vector_type(8))) _Float16;
using f32x4  = __attribute__((ext_vector_type(4))) float;

constexpr int Bdim = 16;
constexpr int Tdim = 1024;
constexpr int Sdim = 1024;
constexpr int Ddim = 1024;

__device__ __forceinline__ unsigned short f2hu(float x) {
  _Float16 h = (_Float16)x;
  return __builtin_bit_cast(unsigned short, h);
}
__device__ __forceinline__ float hu2f(unsigned short u) {
  return (float)__builtin_bit_cast(_Float16, u);
}

// ---------- fp32 -> fp16 single ----------
__global__ void __launch_bounds__(256)
conv_kernel(const float* __restrict__ src, unsigned short* __restrict__ dst, int n4) {
  int i = blockIdx.x * blockDim.x + threadIdx.x;
  int stride = gridDim.x * blockDim.x;
  for (; i < n4; i += stride) {
    float4 v = reinterpret_cast<const float4*>(src)[i];
    ushort4 h;
    h.x = f2hu(v.x); h.y = f2hu(v.y); h.z = f2hu(v.z); h.w = f2hu(v.w);
    reinterpret_cast<ushort4*>(dst)[i] = h;
  }
}

// ---------- ctx [B,S,D] fp32 -> ctx16 [B,S,D] fp16 AND ctxT [B,D,S] fp16 ----------
__global__ void __launch_bounds__(256)
ctxprep_kernel(const float* __restrict__ ctx, unsigned short* __restrict__ ctx16,
               unsigned short* __restrict__ ctxT) {
  __shared__ float tile[64][65];
  int b = blockIdx.z;
  int d0 = blockIdx.x * 64, s0 = blockIdx.y * 64;
  const float* src = ctx + (size_t)b * Sdim * Ddim;
  unsigned short* dstS = ctx16 + (size_t)b * Sdim * Ddim;
  unsigned short* dstT = ctxT + (size_t)b * Ddim * Sdim;
  int tx = threadIdx.x & 15, ty = threadIdx.x >> 4;
  #pragma unroll
  for (int r = 0; r < 4; ++r) {
    int s = ty + r * 16;
    float4 v = reinterpret_cast<const float4*>(src + (size_t)(s0 + s) * Ddim + d0)[tx];
    ushort4 hs;
    hs.x = f2hu(v.x); hs.y = f2hu(v.y); hs.z = f2hu(v.z); hs.w = f2hu(v.w);
    reinterpret_cast<ushort4*>(dstS + (size_t)(s0 + s) * Ddim + d0)[tx] = hs;
    tile[s][tx * 4 + 0] = v.x; tile[s][tx * 4 + 1] = v.y;
    tile[s][tx * 4 + 2] = v.z; tile[s][tx * 4 + 3] = v.w;
  }
  __syncthreads();
  #pragma unroll
  for (int r = 0; r < 4; ++r) {
    int d = ty + r * 16;
    ushort4 o;
    o.x = f2hu(tile[tx * 4 + 0][d]);
    o.y = f2hu(tile[tx * 4 + 1][d]);
    o.z = f2hu(tile[tx * 4 + 2][d]);
    o.w = f2hu(tile[tx * 4 + 3][d]);
    reinterpret_cast<ushort4*>(dstT + (size_t)(d0 + d) * Sdim + s0)[tx] = o;
  }
}

#define MFMAH(d, x, y)                                                          \
  d = __builtin_amdgcn_mfma_f32_16x16x32_f16(__builtin_bit_cast(half8, (x)),    \
                                             __builtin_bit_cast(half8, (y)), (d), 0, 0, 0)

#define GLOADLDS(g, l)                                                          \
  __builtin_amdgcn_global_load_lds((const __attribute__((address_space(1))) void*)(g), \
                                   (__attribute__((address_space(3))) void*)(l), 16, 0, 0)

// ---------- PLAIN fp16 GEMM: 256x256 tile, BK=128, SINGLE 128 KiB buffer, NT=8 ----------
// (r13 configuration — session best, 182.8 µs total, verified passing)
// Round: wait t -> read kk0/1 frags -> MFMA -> read kk2/3 frags -> barrier(all reads
// retired) -> restage t+1 into same buffer -> MFMA under DMA.
// 256B rows, 16 granules; swizzle pg = g ^ (row&15) (full XOR perm per 16 lanes).
// MODE 1: out f32 at (rr*16+bb)*1024+cc ; MODE 2: out fp16 at rr*1024+cc
template <int MODE>
__global__ void __launch_bounds__(512, 2)
gemmP(const unsigned short* __restrict__ Ag, const unsigned short* __restrict__ Bg,
      size_t aBatch, size_t bBatch, int mnShift,
      unsigned short* __restrict__ outH, float* __restrict__ outF) {
  constexpr int NT = 8;                              // BK = 128
  __shared__ __align__(16) unsigned short lds[65536]; // A[256][128] | B[256][128]

  const int hw = blockIdx.x;
  const int L  = (hw & 7) * 32 + (hw >> 3);
  const int bb = L >> mnShift;
  const int r  = L & ((1 << mnShift) - 1);
  const int m0 = (r >> 2) * 256;
  const int n0 = (r & 3) * 256;

  const int tid  = threadIdx.x;
  const int lane = tid & 63;
  const int w    = tid >> 6;          // 8 waves: 2(M) x 4(N)
  const int wr   = (w >> 2) * 128;
  const int wc   = (w & 3) * 64;
  const int l15  = lane & 15;
  const int g0   = lane >> 4;

  // staging: thread covers granule (srow16 + i*32, sg); row&15 == srow16&15 (i*32≡0 mod 16)
  const int srow16 = tid >> 4;        // 0..31
  const int sg     = tid & 15;
  const int rs     = srow16 & 15;
  const unsigned short* spA = Ag + (size_t)bb * aBatch + (size_t)(m0 + srow16) * 1024 + ((sg ^ rs) * 8);
  const unsigned short* spB = Bg + (size_t)bb * bBatch + (size_t)(n0 + srow16) * 1024 + ((sg ^ rs) * 8);
  unsigned short* const ldA = lds + srow16 * 128 + sg * 8;          // linear dest (DMA req)
  unsigned short* const ldB = ldA + 32768;

  auto stage = [&](int kt) {          // 16 loads/thread = full 128 KB tile
    #pragma unroll
    for (int i = 0; i < 8; ++i) {
      GLOADLDS(spA + (size_t)i * (32 * 1024) + kt * 128, ldA + i * 4096);
      GLOADLDS(spB + (size_t)i * (32 * 1024) + kt * 128, ldB + i * 4096);
    }
  };

  f32x4 acc[8][4];
  const f32x4 vzero = {0.f, 0.f, 0.f, 0.f};
  #pragma unroll
  for (int f = 0; f < 8; ++f)
    #pragma unroll
    for (int j = 0; j < 4; ++j) acc[f][j] = vzero;

  stage(0);

  #pragma unroll 1
  for (int t = 0; t < NT; ++t) {
    asm volatile("s_waitcnt vmcnt(0)" ::: "memory");   // tile t fully in LDS
    __builtin_amdgcn_s_barrier();
    asm volatile("" ::: "memory");

    short8 af[8][2], bf[4][2];

    // ---- half 0: logical granules kk*4+g0, kk in {0,1} ----
    #pragma unroll
    for (int j = 0; j < 4; ++j) {
      const int row = wc + j * 16 + l15;
      #pragma unroll
      for (int kk = 0; kk < 2; ++kk)
        bf[j][kk] = *reinterpret_cast<const short8*>(lds + 32768 + row * 128 + ((kk * 4 + g0) ^ l15) * 8);
    }
    #pragma unroll
    for (int f = 0; f < 8; ++f) {
      const int row = wr + f * 16 + l15;
      #pragma unroll
      for (int kk = 0; kk < 2; ++kk)
        af[f][kk] = *reinterpret_cast<const short8*>(lds + row * 128 + ((kk * 4 + g0) ^ l15) * 8);
    }
    asm volatile("s_waitcnt lgkmcnt(0)" ::: "memory");
    __builtin_amdgcn_sched_barrier(0);
    __builtin_amdgcn_s_setprio(1);
    #pragma unroll
    for (int f = 0; f < 8; ++f)
      #pragma unroll
      for (int j = 0; j < 4; ++j)
        #pragma unroll
        for (int kk = 0; kk < 2; ++kk)
          MFMAH(acc[f][j], af[f][kk], bf[j][kk]);
    __builtin_amdgcn_s_setprio(0);
    __builtin_amdgcn_sched_barrier(0);     // cap live ranges: half-1 reads stay below

    // ---- half 1: logical granules (kk+2)*4+g0, kk in {0,1} ----
    #pragma unroll
    for (int j = 0; j < 4; ++j) {
      const int row = wc + j * 16 + l15;
      #pragma unroll
      for (int kk = 0; kk < 2; ++kk)
        bf[j][kk] = *reinterpret_cast<const short8*>(lds + 32768 + row * 128 + (((kk + 2) * 4 + g0) ^ l15) * 8);
    }
    #pragma unroll
    for (int f = 0; f < 8; ++f) {
      const int row = wr + f * 16 + l15;
      #pragma unroll
      for (int kk = 0; kk < 2; ++kk)
        af[f][kk] = *reinterpret_cast<const short8*>(lds + row * 128 + (((kk + 2) * 4 + g0) ^ l15) * 8);
    }
    asm volatile("s_waitcnt lgkmcnt(0)" ::: "memory");
    __builtin_amdgcn_sched_barrier(0);
    __builtin_amdgcn_s_barrier();          // ALL reads of tile t retired -> buffer free

    if (t + 1 < NT) stage(t + 1);          // restage into same buffer, under MFMA

    __builtin_amdgcn_s_setprio(1);
    #pragma unroll
    for (int f = 0; f < 8; ++f)
      #pragma unroll
      for (int j = 0; j < 4; ++j)
        #pragma unroll
        for (int kk = 0; kk < 2; ++kk)
          MFMAH(acc[f][j], af[f][kk], bf[j][kk]);
    __builtin_amdgcn_s_setprio(0);
  }

  // epilogue: C/D layout col=lane&15, row=(lane>>4)*4+q (m89/m91 verified)
  const int lr = (lane >> 4) * 4;
  const int lc = lane & 15;
  #pragma unroll
  for (int f = 0; f < 8; ++f)
    #pragma unroll
    for (int j = 0; j < 4; ++j)
      #pragma unroll
      for (int q = 0; q < 4; ++q) {
        int rr = m0 + wr + f * 16 + lr + q;
        int cc = n0 + wc + j * 16 + lc;
        float v = acc[f][j][q];
        if constexpr (MODE == 2) {
          outH[(size_t)rr * 1024 + cc] = f2hu(v);
        } else {
          outF[((size_t)rr * 16 + bb) * 1024 + cc] = v;
        }
      }
}

// ---------- FUSED K2+softmax: 64x1024 tile (full S row), BK=64, NT=16 ----------
// (unchanged from r11-r13 — verified passing)
__global__ void __launch_bounds__(512, 2)
gemmF(const unsigned short* __restrict__ Hh, const unsigned short* __restrict__ Cg,
      float* __restrict__ alignOut, unsigned short* __restrict__ pOut) {
  constexpr int NT = 16;
  __shared__ __align__(16) unsigned short lds[2 * 4096 + 65536];  // A dbuf + B

  const int hw = blockIdx.x;                 // 256 blocks
  const int L  = (hw & 7) * 32 + (hw >> 3);  // XCD-chunked
  const int bb = L >> 4;                     // 16 batches
  const int m0 = (L & 15) * 64;              // 16 M-blocks of 64 rows

  const int tid  = threadIdx.x;
  const int lane = tid & 63;
  const int w    = tid >> 6;          // 8 waves: 1(M) x 8(N)
  const int l15  = lane & 15;
  const int g0   = lane >> 4;

  const int srow = tid >> 3;          // 0..63
  const int sg   = tid & 7;
  const int rs   = srow & 7;
  const unsigned short* spA = Hh + (size_t)bb * (Tdim * Ddim) + (size_t)(m0 + srow) * 1024 + ((sg ^ rs) * 8);
  const unsigned short* spB = Cg + (size_t)bb * (Sdim * Ddim) + (size_t)srow * 1024 + ((sg ^ rs) * 8);

  unsigned short* const ldsB = lds + 8192;

  auto stageA = [&](int buf, int kt) {       // 1 instr/thread (8KB tile)
    GLOADLDS(spA + kt * 64, lds + buf * 4096 + tid * 8);
  };
  auto stageB = [&](int kt) {                // 16 instr/thread (128KB)
    #pragma unroll
    for (int i = 0; i < 16; ++i)
      GLOADLDS(spB + (size_t)i * (64 * 1024) + kt * 64, ldsB + i * 4096 + tid * 8);
  };

  f32x4 acc[4][8];
  const f32x4 vzero = {0.f, 0.f, 0.f, 0.f};
  #pragma unroll
  for (int f = 0; f < 4; ++f)
    #pragma unroll
    for (int j = 0; j < 8; ++j) acc[f][j] = vzero;

  stageA(0, 0);
  stageB(0);
  stageA(1, 1);
  asm volatile("s_waitcnt vmcnt(1)" ::: "memory");
  __builtin_amdgcn_s_barrier();

  #pragma unroll 1
  for (int t = 0; t < NT; ++t) {
    const unsigned short* tA = lds + (t & 1) * 4096;

    short8 bf[8][2];
    #pragma unroll
    for (int j = 0; j < 8; ++j) {
      const int row = w * 128 + j * 16 + l15;
      #pragma unroll
      for (int kk = 0; kk < 2; ++kk)
        bf[j][kk] = *reinterpret_cast<const short8*>(ldsB + row * 64 + ((kk * 4 + g0) ^ (row & 7)) * 8);
    }
    short8 af[4][2];
    #pragma unroll
    for (int f = 0; f < 4; ++f) {
      const int row = f * 16 + l15;
      #pragma unroll
      for (int kk = 0; kk < 2; ++kk)
        af[f][kk] = *reinterpret_cast<const short8*>(tA + row * 64 + ((kk * 4 + g0) ^ (row & 7)) * 8);
    }
    asm volatile("s_waitcnt lgkmcnt(0)" ::: "memory");
    __builtin_amdgcn_sched_barrier(0);
    __builtin_amdgcn_s_barrier();          // all LDS reads retired -> buffers free

    if (t + 1 < NT) stageB(t + 1);         // restage B under MFMA phase
    if (t + 2 < NT) stageA(t & 1, t + 2);

    __builtin_amdgcn_s_setprio(1);
    #pragma unroll
    for (int f = 0; f < 4; ++f)
      #pragma unroll
      for (int j = 0; j < 8; ++j)
        #pragma unroll
        for (int kk = 0; kk < 2; ++kk)
          MFMAH(acc[f][j], af[f][kk], bf[j][kk]);
    __builtin_amdgcn_s_setprio(0);

    if (t + 1 < NT) {
      if (t + 2 < NT) asm volatile("s_waitcnt vmcnt(1)" ::: "memory");
      else            asm volatile("s_waitcnt vmcnt(0)" ::: "memory");
    }
    __builtin_amdgcn_s_barrier();
  }

  // ---- fused row softmax over full S=1024 ----
  float* red = (float*)lds;                 // reuse A region: [64][8] f32
  const int lr = (lane >> 4) * 4;

  float rmax[4][4];
  #pragma unroll
  for (int f = 0; f < 4; ++f)
    #pragma unroll
    for (int q = 0; q < 4; ++q) {
      float m = acc[f][0][q];
      #pragma unroll
      for (int j = 1; j < 8; ++j) m = fmaxf(m, acc[f][j][q]);
      #pragma unroll
      for (int o = 1; o < 16; o <<= 1) m = fmaxf(m, __shfl_xor(m, o));
      rmax[f][q] = m;
    }
  if (l15 == 0) {
    #pragma unroll
    for (int f = 0; f < 4; ++f)
      #pragma unroll
      for (int q = 0; q < 4; ++q) red[(f * 16 + lr + q) * 8 + w] = rmax[f][q];
  }
  __syncthreads();
  #pragma unroll
  for (int f = 0; f < 4; ++f)
    #pragma unroll
    for (int q = 0; q < 4; ++q) {
      const float* rr = red + (f * 16 + lr + q) * 8;
      float m = rr[0];
      #pragma unroll
      for (int k = 1; k < 8; ++k) m = fmaxf(m, rr[k]);
      rmax[f][q] = m;
    }
  __syncthreads();

  float rsum[4][4];
  #pragma unroll
  for (int f = 0; f < 4; ++f)
    #pragma unroll
    for (int q = 0; q < 4; ++q) {
      float s = 0.f;
      #pragma unroll
      for (int j = 0; j < 8; ++j) {
        float e = __expf(acc[f][j][q] - rmax[f][q]);
        acc[f][j][q] = e;
        s += e;
      }
      #pragma unroll
      for (int o = 1; o < 16; o <<= 1) s += __shfl_xor(s, o);
      rsum[f][q] = s;
    }
  if (l15 == 0) {
    #pragma unroll
    for (int f = 0; f < 4; ++f)
      #pragma unroll
      for (int q = 0; q < 4; ++q) red[(f * 16 + lr + q) * 8 + w] = rsum[f][q];
  }
  __syncthreads();
  #pragma unroll
  for (int f = 0; f < 4; ++f)
    #pragma unroll
    for (int q = 0; q < 4; ++q) {
      const float* rr = red + (f * 16 + lr + q) * 8;
      float s = ((rr[0] + rr[1]) + (rr[2] + rr[3])) + ((rr[4] + rr[5]) + (rr[6] + rr[7]));
      rsum[f][q] = 1.0f / s;
    }

  #pragma unroll
  for (int f = 0; f < 4; ++f)
    #pragma unroll
    for (int q = 0; q < 4; ++q) {
      const int row = m0 + f * 16 + lr + q;
      float inv = rsum[f][q];
      #pragma unroll
      for (int j = 0; j < 8; ++j) {
        const int cc = w * 128 + j * 16 + l15;
        float v = acc[f][j][q] * inv;
        alignOut[((size_t)row * 16 + bb) * 1024 + cc] = v;
        pOut[((size_t)bb * 1024 + row) * 1024 + cc] = f2hu(v);
      }
    }
}

extern "C" void kernel_launch(void* const* d_in, const int* in_sizes, int n_in,
                              void* d_out, int out_size, void* d_ws, size_t ws_size,
                              hipStream_t stream) {
  const float* input = (const float*)d_in[0];  // [B,T,D]
  const float* ctx   = (const float*)d_in[1];  // [B,S,D]
  const float* Wt    = (const float*)d_in[2];  // [D,D]
  float* attn_out  = (float*)d_out;                               // [T,B,D]
  float* align_out = attn_out + (size_t)Tdim * Bdim * Ddim;       // [T,B,S]

  const size_t NE = (size_t)Bdim * Tdim * Ddim;  // 16M elems
  unsigned short* x16  = (unsigned short*)d_ws;  // 32MB, reused as ctx16 after K1
  unsigned short* Wh   = x16 + NE;               // 2MB
  unsigned short* hh   = Wh + (size_t)Ddim * Ddim;  // 32MB, overwritten by p in gemmF
  unsigned short* ctxT = hh + NE;                // 32MB
  unsigned short* ctx16 = x16;
  unsigned short* p     = hh;

  conv_kernel<<<2048, 256, 0, stream>>>(input, x16, (int)(NE / 4));
  conv_kernel<<<512, 256, 0, stream>>>(Wt, Wh, (int)((size_t)Ddim * Ddim / 4));
  // K1: h = x @ W^T, plain fp16 -> hh
  gemmP<2><<<256, 512, 0, stream>>>(x16, Wh, 0, 0, 8, hh, nullptr);
  // ctx16 [B,S,D] + ctxT [B,D,S] fp16 (ctx16 into dead x region)
  ctxprep_kernel<<<dim3(16, 16, Bdim), 256, 0, stream>>>(ctx, ctx16, ctxT);
  // K2 fused: align = softmax(h @ ctx^T) -> align_out f32 [T,B,S], p fp16
  gemmF<<<256, 512, 0, stream>>>(hh, ctx16, align_out, p);
  // K4: attn = p @ ctx, plain fp16 -> f32 [T,B,D]
  gemmP<1><<<256, 512, 0, stream>>>(p, ctxT, (size_t)Tdim * Sdim,
                                    (size_t)Ddim * Sdim, 4, nullptr, attn_out);
}